// Round 10
// baseline (387.838 us; speedup 1.0000x reference)
//
#include <hip/hip_runtime.h>
#include <hip/hip_bf16.h>
#include <math.h>

typedef unsigned short u16;
typedef __attribute__((ext_vector_type(8))) short bf16x8;   // 8 bf16 = 4 VGPRs
typedef __attribute__((ext_vector_type(4))) float f32x4;

// ---------- helpers ----------
__device__ static inline u16 f2bf(float f) {
  unsigned u = __float_as_uint(f);
  u += 0x7fff + ((u >> 16) & 1);          // RNE; inputs are finite normals
  return (u16)(u >> 16);
}

__device__ static inline void gload_lds16(const void* g, void* l) {
  __builtin_amdgcn_global_load_lds(
      (const __attribute__((address_space(1))) unsigned int*)g,
      (__attribute__((address_space(3))) unsigned int*)l, 16, 0, 0);
}

__device__ static inline void store_out(u16* p, float v)   { *p = f2bf(v); }
__device__ static inline void store_out(float* p, float v) { *p = v; }

// ---------- fp32 -> bf16 convert ----------
__global__ void cvt_f32_bf16(const float* __restrict__ src, u16* __restrict__ dst, int n) {
  int stride = gridDim.x * blockDim.x;
  for (int i = blockIdx.x * blockDim.x + threadIdx.x; i * 8 < n; i += stride) {
    const float4* s4 = (const float4*)(src + (size_t)i * 8);
    float4 a = s4[0], b = s4[1];
    u16 t[8] = { f2bf(a.x), f2bf(a.y), f2bf(a.z), f2bf(a.w),
                 f2bf(b.x), f2bf(b.y), f2bf(b.z), f2bf(b.w) };
    *(bf16x8*)(dst + (size_t)i * 8) = *(bf16x8*)t;
  }
}

// three 2048x2048 weights in one launch (wq,wk,wv -> packed Wqkv)
__global__ void cvt3_f32_bf16(const float* __restrict__ s0, const float* __restrict__ s1,
                              const float* __restrict__ s2, u16* __restrict__ dst) {
  const float* s = blockIdx.y == 0 ? s0 : (blockIdx.y == 1 ? s1 : s2);
  size_t i = ((size_t)blockIdx.x * blockDim.x + threadIdx.x) * 8;
  const float4* s4 = (const float4*)(s + i);
  float4 a = s4[0], b = s4[1];
  u16 t[8] = { f2bf(a.x), f2bf(a.y), f2bf(a.z), f2bf(a.w),
               f2bf(b.x), f2bf(b.y), f2bf(b.z), f2bf(b.w) };
  *(bf16x8*)(dst + (size_t)blockIdx.y * 4194304 + i) = *(bf16x8*)t;
}

// ---------- GEMM 256xBN 4-phase pipelined, C = A * B^T ----------
// BN = NF*64. 8 waves (2M x 4N), per-wave 128 x NF*16 output, BK=64,
// double-buffered LDS, XOR swizzle, counted vmcnt(NF) at K-tile boundary
// (same ledger as the verified 2-phase: B(t+2) stays in flight).
// 4 phases/K-tile: {ds-subtile || stage-half || bar || lgkm0 || MFMA || bar}.
template <int NF, typename OutT>
__global__ __launch_bounds__(512, 2)
void gemm4ph(const u16* __restrict__ A, const u16* __restrict__ Bm,
             OutT* __restrict__ C, int M, int N, int K) {
  constexpr int BN = NF * 64;
  constexpr int NA = (NF + 1) / 2;       // 3->2, 2->1
  constexpr int NB = NF - NA;            // ->1
  __shared__ u16 Abuf[2][256 * 64];
  __shared__ u16 Bbuf[2][BN * 64];
  const int tid = threadIdx.x, lane = tid & 63, w = tid >> 6;
  const int wm = w >> 2, wn = w & 3;
  const int g = lane >> 4, l16 = lane & 15;

  const int per = gridDim.x >> 3;        // bijective XCD swizzle (grid%8==0)
  const int swz = ((int)blockIdx.x & 7) * per + ((int)blockIdx.x >> 3);
  const int nx = N / BN;
  const int bx = swz % nx, by = swz / nx;
  const int brow = by << 8, bcol = bx * BN;
  const int nt = K >> 6;

  auto stage_Ah = [&](int h, int kt, int d) {
    char* lds = (char*)Abuf[d] + h * 16384;
#pragma unroll
    for (int i = 0; i < 2; ++i) {
      int idx = i * 512 + tid;
      int r = h * 128 + (idx >> 3);
      int c = ((idx & 7) * 16) ^ ((r & 7) << 4);
      gload_lds16((const char*)(A + (size_t)(brow + r) * K + kt * 64) + c,
                  lds + idx * 16);
    }
  };
  auto stage_B = [&](int kt, int d) {
    char* lds = (char*)Bbuf[d];
#pragma unroll
    for (int i = 0; i < NF; ++i) {
      int idx = i * 512 + tid;
      int r = idx >> 3;
      int c = ((idx & 7) * 16) ^ ((r & 7) << 4);
      gload_lds16((const char*)(Bm + (size_t)(bcol + r) * K + kt * 64) + c,
                  lds + idx * 16);
    }
  };

  f32x4 acc[8][NF] = {};
  bf16x8 afr[4][2], bfrA[NA][2], bfrB[NB][2];

  auto lda = [&](int d, int mf0) {
#pragma unroll
    for (int mf = 0; mf < 4; ++mf) {
      int r = wm * 128 + (mf0 + mf) * 16 + l16;
      const char* base = (const char*)Abuf[d] + r * 128;
      int sw = (r & 7) << 4;
#pragma unroll
      for (int ks = 0; ks < 2; ++ks)
        afr[mf][ks] = *(const bf16x8*)(base + ((ks * 64 + g * 16) ^ sw));
    }
  };
  auto ldbA = [&](int d) {
#pragma unroll
    for (int nf = 0; nf < NA; ++nf) {
      int r = wn * (NF * 16) + nf * 16 + l16;
      const char* base = (const char*)Bbuf[d] + r * 128;
      int sw = (r & 7) << 4;
#pragma unroll
      for (int ks = 0; ks < 2; ++ks)
        bfrA[nf][ks] = *(const bf16x8*)(base + ((ks * 64 + g * 16) ^ sw));
    }
  };
  auto ldbB = [&](int d) {
#pragma unroll
    for (int nf = 0; nf < NB; ++nf) {
      int r = wn * (NF * 16) + (NA + nf) * 16 + l16;
      const char* base = (const char*)Bbuf[d] + r * 128;
      int sw = (r & 7) << 4;
#pragma unroll
      for (int ks = 0; ks < 2; ++ks)
        bfrB[nf][ks] = *(const bf16x8*)(base + ((ks * 64 + g * 16) ^ sw));
    }
  };
  auto mmaA = [&](int mf0) {
    __builtin_amdgcn_s_setprio(1);
#pragma unroll
    for (int mf = 0; mf < 4; ++mf)
#pragma unroll
      for (int nf = 0; nf < NA; ++nf)
#pragma unroll
        for (int ks = 0; ks < 2; ++ks)
          acc[mf0 + mf][nf] = __builtin_amdgcn_mfma_f32_16x16x32_bf16(
              afr[mf][ks], bfrA[nf][ks], acc[mf0 + mf][nf], 0, 0, 0);
    __builtin_amdgcn_s_setprio(0);
  };
  auto mmaB = [&](int mf0) {
    __builtin_amdgcn_s_setprio(1);
#pragma unroll
    for (int mf = 0; mf < 4; ++mf)
#pragma unroll
      for (int nf = 0; nf < NB; ++nf)
#pragma unroll
        for (int ks = 0; ks < 2; ++ks)
          acc[mf0 + mf][NA + nf] = __builtin_amdgcn_mfma_f32_16x16x32_bf16(
              afr[mf][ks], bfrB[nf][ks], acc[mf0 + mf][NA + nf], 0, 0, 0);
    __builtin_amdgcn_s_setprio(0);
  };

#define WAIT_LGKM() do { \
    asm volatile("s_waitcnt lgkmcnt(0)" ::: "memory"); \
    __builtin_amdgcn_sched_barrier(0); } while (0)
#define WAIT_VM_NF() do { \
    if constexpr (NF == 3) asm volatile("s_waitcnt vmcnt(3)" ::: "memory"); \
    else                   asm volatile("s_waitcnt vmcnt(2)" ::: "memory"); \
    __builtin_amdgcn_sched_barrier(0); } while (0)

  // prologue: tile0 -> buf0, B(1) -> buf1 (stays in flight across the wait)
  stage_Ah(0, 0, 0); stage_Ah(1, 0, 0);
  stage_B(0, 0);
  stage_B(1, 1);
  WAIT_VM_NF();
  __builtin_amdgcn_s_barrier();

  for (int t = 0; t < nt; ++t) {
    const int cur = t & 1;
    // P1: lda(m0-3)+ldbA; stage A.h0(t+1); MFMA (m0-3) x nA
    lda(cur, 0); ldbA(cur);
    if (t + 1 < nt) stage_Ah(0, t + 1, cur ^ 1);
    __builtin_amdgcn_s_barrier();
    WAIT_LGKM();
    mmaA(0);
    __builtin_amdgcn_s_barrier();
    // P2: ldbB; stage A.h1(t+1); MFMA (m0-3) x nB
    ldbB(cur);
    if (t + 1 < nt) stage_Ah(1, t + 1, cur ^ 1);
    __builtin_amdgcn_s_barrier();
    WAIT_LGKM();
    mmaB(0);
    __builtin_amdgcn_s_barrier();
    // P3: lda(m4-7); stage B(t+2) -> buf[cur] (B region dead: all waves'
    //     Bbuf[cur] reads completed before P2's post-MFMA barrier)
    lda(cur, 4);
    if (t + 2 < nt) stage_B(t + 2, cur);
    __builtin_amdgcn_s_barrier();
    WAIT_LGKM();
    mmaB(4);
    __builtin_amdgcn_s_barrier();
    // P4: MFMA (m4-7) x nA from live regs; boundary counted drain
    mmaA(4);
    if (t + 1 < nt) {
      if (t + 2 < nt) { WAIT_VM_NF(); }
      else {
        asm volatile("s_waitcnt vmcnt(0)" ::: "memory");
        __builtin_amdgcn_sched_barrier(0);
      }
      __builtin_amdgcn_s_barrier();
    }
  }
#undef WAIT_LGKM
#undef WAIT_VM_NF

  const size_t cb = (size_t)(brow + wm * 128) * N + bcol + wn * (NF * 16);
#pragma unroll
  for (int mf = 0; mf < 8; ++mf)
#pragma unroll
    for (int nf = 0; nf < NF; ++nf) {
      int col = nf * 16 + l16;
#pragma unroll
      for (int rr = 0; rr < 4; ++rr) {
        int row = mf * 16 + g * 4 + rr;
        store_out(C + cb + (size_t)row * N + col, acc[mf][nf][rr]);
      }
    }
}

// ---------- V transpose: QKV V-part [b,s,h*128+d] -> Vt [b,h,d,s] ----------
__global__ __launch_bounds__(256)
void transpose_v(const u16* __restrict__ QKV, u16* __restrict__ Vt) {
  __shared__ u16 t[64][72];
  const int tid = threadIdx.x;
  const int b = blockIdx.y >> 5;
  const int s0 = (blockIdx.y & 31) * 64;
  const int hd0 = blockIdx.x * 64;
  const int lr = tid >> 2, lc = (tid & 3) * 16;
  const u16* src = QKV + ((size_t)(b * 2048 + s0 + lr) * 6144 + 4096 + hd0 + lc);
  *(bf16x8*)&t[lr][lc]     = *(const bf16x8*)src;
  *(bf16x8*)&t[lr][lc + 8] = *(const bf16x8*)(src + 8);
  __syncthreads();
  u16 tmp[16];
#pragma unroll
  for (int j = 0; j < 16; ++j) tmp[j] = t[lc + j][lr];
  u16* dst = Vt + ((size_t)(b * 2048 + hd0 + lr) * 2048 + s0 + lc);
  *(bf16x8*)dst       = *(bf16x8*)tmp;
  *(bf16x8*)(dst + 8) = *(bf16x8*)(tmp + 8);
}

// ---------- causal flash attention v4 ----------
// v3 + T13 defer-max (skip O-rescale when max growth <= 8) + exp-skip for
// wave-uniformly masked kb blocks.
__global__ __launch_bounds__(256, 2)
void attn_fwd(const u16* __restrict__ QKV, const u16* __restrict__ Vt,
              u16* __restrict__ AO) {
  __shared__ u16 Ks[2][64 * 128];
  __shared__ u16 Vs[2][128 * 64];
  __shared__ u16 Ps[4][16 * 64];
  const int tid = threadIdx.x, lane = tid & 63, w = tid >> 6;
  const int g = lane >> 4, l16 = lane & 15;
  const int bh = blockIdx.y, b = bh >> 4, h = bh & 15;
  const int fold = blockIdx.x;
  const int pswz = (l16 & 7) << 4;

  for (int phase = 0; phase < 2; ++phase) {
    const int qt = phase == 0 ? fold : 31 - fold;
    const int q0 = qt * 64 + w * 16;

    bf16x8 qf[4];
    {
      const u16* qrow = QKV + ((size_t)(b * 2048 + q0 + l16) * 6144 + h * 128 + g * 8);
#pragma unroll
      for (int c = 0; c < 4; ++c) qf[c] = *(const bf16x8*)(qrow + c * 32);
    }
    f32x4 o[8] = {};
    float mrun = -INFINITY, lrun = 0.f;

    auto stage = [&](int it, int d) {
      int kv0 = it * 64;
#pragma unroll
      for (int i = 0; i < 4; ++i) {
        int idx = i * 256 + tid;
        {
          int row = idx >> 4;
          int scolb = ((idx & 15) * 16) ^ ((row & 7) << 4);
          gload_lds16((const char*)QKV +
                          ((size_t)(b * 2048 + kv0 + row) * 6144 + 2048 + h * 128) * 2 + scolb,
                      (char*)Ks[d] + idx * 16);
        }
        {
          int dd = idx >> 3;
          int vcolb = ((idx & 7) * 16) ^ ((dd & 7) << 4);
          gload_lds16((const char*)Vt + ((size_t)(bh * 128 + dd) * 2048 + kv0) * 2 + vcolb,
                      (char*)Vs[d] + idx * 16);
        }
      }
    };

    const int ntkv = qt + 1;
    stage(0, 0);
    for (int it = 0; it < ntkv; ++it) {
      const int kv0 = it * 64, cur = it & 1;
      if (it + 1 < ntkv) {
        stage(it + 1, cur ^ 1);                       // prefetch over this tile's compute
        asm volatile("s_waitcnt vmcnt(8)" ::: "memory");
      } else {
        asm volatile("s_waitcnt vmcnt(0)" ::: "memory");
      }
      __builtin_amdgcn_sched_barrier(0);
      __builtin_amdgcn_s_barrier();

      // swapped QK^T: s[kb][r] = S[k=kv0+kb*16+g*4+r][q=q0+l16]
      f32x4 s[4];
#pragma unroll
      for (int kb = 0; kb < 4; ++kb) {
        if (kv0 + kb * 16 > q0 + 15) {                // wave-uniform masked block
          s[kb] = f32x4{-INFINITY, -INFINITY, -INFINITY, -INFINITY};
          continue;
        }
        f32x4 a = {};
        int row = kb * 16 + l16;
        int swzk = (row & 7) << 4;
#pragma unroll
        for (int c = 0; c < 4; ++c) {
          bf16x8 kf = *(const bf16x8*)((const char*)Ks[cur] + row * 256 + ((c * 64 + g * 16) ^ swzk));
          a = __builtin_amdgcn_mfma_f32_16x16x32_bf16(kf, qf[c], a, 0, 0, 0);
        }
        s[kb] = a * 0.08838834764831845f;             // 1/sqrt(128)
      }
      if (kv0 == qt * 64) {                           // diagonal tile: elementwise mask
#pragma unroll
        for (int kb = 0; kb < 4; ++kb)
#pragma unroll
          for (int r = 0; r < 4; ++r)
            if (kv0 + kb * 16 + g * 4 + r > q0 + l16) s[kb][r] = -INFINITY;
      }

      // online-softmax stats for q = q0 + l16 (scalar per thread)
      float mloc = -INFINITY;
#pragma unroll
      for (int kb = 0; kb < 4; ++kb)
#pragma unroll
        for (int r = 0; r < 4; ++r) mloc = fmaxf(mloc, s[kb][r]);
      mloc = fmaxf(mloc, __shfl_xor(mloc, 16));
      mloc = fmaxf(mloc, __shfl_xor(mloc, 32));
      float mnew = fmaxf(mrun, mloc);
      // T13 defer-max: only rescale when growth exceeds threshold (wave-uniform)
      if (!__all(mnew - mrun <= 8.f)) {
        float al = __expf(mrun - mnew);
        mrun = mnew;
        lrun *= al;
        float alq[4];
#pragma unroll
        for (int r = 0; r < 4; ++r) alq[r] = __shfl(al, g * 4 + r);
#pragma unroll
        for (int db = 0; db < 8; ++db)
#pragma unroll
          for (int r = 0; r < 4; ++r) o[db][r] *= alq[r];
      }
      float rsum = 0.f;
#pragma unroll
      for (int kb = 0; kb < 4; ++kb) {
        if (kv0 + kb * 16 > q0 + 15) {                // masked: P=0, skip exps
          *(ushort4*)((char*)Ps[w] + l16 * 128 + ((kb * 32 + g * 8) ^ pswz)) = ushort4{0, 0, 0, 0};
          continue;
        }
        float p0 = __expf(s[kb][0] - mrun);
        float p1 = __expf(s[kb][1] - mrun);
        float p2 = __expf(s[kb][2] - mrun);
        float p3 = __expf(s[kb][3] - mrun);
        rsum += (p0 + p1) + (p2 + p3);
        ushort4 pk = { f2bf(p0), f2bf(p1), f2bf(p2), f2bf(p3) };
        *(ushort4*)((char*)Ps[w] + l16 * 128 + ((kb * 32 + g * 8) ^ pswz)) = pk;
      }
      rsum += __shfl_xor(rsum, 16);
      rsum += __shfl_xor(rsum, 32);
      lrun += rsum;

      // PV: A = P rows q=l16, B = V^T rows d
#pragma unroll
      for (int ks = 0; ks < 2; ++ks) {
        if (kv0 + ks * 32 > q0 + 15) continue;        // fully-masked k-slice (wave-uniform)
        bf16x8 pa = *(const bf16x8*)((const char*)Ps[w] + l16 * 128 + ((ks * 64 + g * 16) ^ pswz));
#pragma unroll
        for (int db = 0; db < 8; ++db) {
          int row = db * 16 + l16;
          int swzv = (row & 7) << 4;
          bf16x8 vf = *(const bf16x8*)((const char*)Vs[cur] + row * 128 + ((ks * 64 + g * 16) ^ swzv));
          o[db] = __builtin_amdgcn_mfma_f32_16x16x32_bf16(pa, vf, o[db], 0, 0, 0);
        }
      }
      __builtin_amdgcn_s_barrier();                   // buf[cur] reads done before restage
    }

    float rlq[4];
#pragma unroll
    for (int r = 0; r < 4; ++r) rlq[r] = 1.0f / __shfl(lrun, g * 4 + r);
#pragma unroll
    for (int r = 0; r < 4; ++r) {
      int q = q0 + g * 4 + r;
#pragma unroll
      for (int db = 0; db < 8; ++db)
        AO[(size_t)(b * 2048 + q) * 2048 + h * 128 + db * 16 + l16] = f2bf(o[db][r] * rlq[r]);
    }
  }
}

// ---------- launch ----------
extern "C" void kernel_launch(void* const* d_in, const int* in_sizes, int n_in,
                              void* d_out, int out_size, void* d_ws, size_t ws_size,
                              hipStream_t stream) {
  const float* x  = (const float*)d_in[0];
  const float* wq = (const float*)d_in[1];
  const float* wk = (const float*)d_in[2];
  const float* wv = (const float*)d_in[3];
  const float* wo = (const float*)d_in[4];
  float* out = (float*)d_out;

  char* ws = (char*)d_ws;
  u16* Xb   = (u16*)(ws);                         // 4096x2048        16 MB
  u16* Wqkv = (u16*)(ws + ((size_t)16 << 20));    // 6144x2048        24 MB
  u16* Wob  = (u16*)(ws + ((size_t)40 << 20));    // 2048x2048         8 MB
  u16* QKV  = (u16*)(ws + ((size_t)48 << 20));    // 4096x6144        48 MB
  u16* Vt   = (u16*)(ws + ((size_t)96 << 20));    // 2x16x128x2048    16 MB
  u16* AO   = (u16*)(ws + ((size_t)112 << 20));   // 4096x2048        16 MB

  cvt_f32_bf16<<<2048, 256, 0, stream>>>(x, Xb, 2 * 2048 * 2048);
  cvt3_f32_bf16<<<dim3(2048, 3), 256, 0, stream>>>(wq, wk, wv, Wqkv);
  cvt_f32_bf16<<<2048, 256, 0, stream>>>(wo, Wob, 2048 * 2048);

  // QKV: 4096x6144x2048, BM=256 BN=192 -> 512 blocks = 2 even rounds
  gemm4ph<3, u16><<<512, 512, 0, stream>>>(Xb, Wqkv, QKV, 4096, 6144, 2048);
  transpose_v<<<dim3(32, 64), 256, 0, stream>>>(QKV, Vt);
  attn_fwd<<<dim3(16, 32), 256, 0, stream>>>(QKV, Vt, AO);
  // WO: 4096x2048x2048, BM=256 BN=128 -> 256 blocks = 1 even round
  gemm4ph<2, float><<<256, 512, 0, stream>>>(AO, Wob, out, 4096, 2048, 2048);
}

// Round 13
// 373.949 us; speedup vs baseline: 1.0371x; 1.0371x over previous
//
#include <hip/hip_runtime.h>
#include <hip/hip_bf16.h>
#include <math.h>

typedef unsigned short u16;
typedef __attribute__((ext_vector_type(8))) short bf16x8;   // 8 bf16 = 4 VGPRs
typedef __attribute__((ext_vector_type(4))) float f32x4;

// ---------- helpers ----------
__device__ static inline u16 f2bf(float f) {
  unsigned u = __float_as_uint(f);
  u += 0x7fff + ((u >> 16) & 1);          // RNE; inputs are finite normals
  return (u16)(u >> 16);
}

__device__ static inline void gload_lds16(const void* g, void* l) {
  __builtin_amdgcn_global_load_lds(
      (const __attribute__((address_space(1))) unsigned int*)g,
      (__attribute__((address_space(3))) unsigned int*)l, 16, 0, 0);
}

__device__ static inline void store_out(u16* p, float v)   { *p = f2bf(v); }
__device__ static inline void store_out(float* p, float v) { *p = v; }

// ---------- fp32 -> bf16 convert ----------
__global__ void cvt_f32_bf16(const float* __restrict__ src, u16* __restrict__ dst, int n) {
  int stride = gridDim.x * blockDim.x;
  for (int i = blockIdx.x * blockDim.x + threadIdx.x; i * 8 < n; i += stride) {
    const float4* s4 = (const float4*)(src + (size_t)i * 8);
    float4 a = s4[0], b = s4[1];
    u16 t[8] = { f2bf(a.x), f2bf(a.y), f2bf(a.z), f2bf(a.w),
                 f2bf(b.x), f2bf(b.y), f2bf(b.z), f2bf(b.w) };
    *(bf16x8*)(dst + (size_t)i * 8) = *(bf16x8*)t;
  }
}

// three 2048x2048 weights in one launch (wq,wk,wv -> packed Wqkv)
__global__ void cvt3_f32_bf16(const float* __restrict__ s0, const float* __restrict__ s1,
                              const float* __restrict__ s2, u16* __restrict__ dst) {
  const float* s = blockIdx.y == 0 ? s0 : (blockIdx.y == 1 ? s1 : s2);
  size_t i = ((size_t)blockIdx.x * blockDim.x + threadIdx.x) * 8;
  const float4* s4 = (const float4*)(s + i);
  float4 a = s4[0], b = s4[1];
  u16 t[8] = { f2bf(a.x), f2bf(a.y), f2bf(a.z), f2bf(a.w),
               f2bf(b.x), f2bf(b.y), f2bf(b.z), f2bf(b.w) };
  *(bf16x8*)(dst + (size_t)blockIdx.y * 4194304 + i) = *(bf16x8*)t;
}

// ---------- GEMM 256xBN 2-phase pipelined, C = A * B^T ----------
// BN = NF*64. 8 waves (2M x 4N), per-wave 128 x NF*16 output, BK=64,
// double-buffered LDS, XOR swizzle (byte ^= (row&7)<<4 on 128B rows),
// counted vmcnt(NF) at K-tile boundaries. Grid sized to divide 256 CUs
// evenly (QKV: NF=3 -> 512 blocks; WO: NF=2 -> 256 blocks).
template <int NF, typename OutT>
__global__ __launch_bounds__(512, 2)
void gemm2ph(const u16* __restrict__ A, const u16* __restrict__ Bm,
             OutT* __restrict__ C, int M, int N, int K) {
  constexpr int BN = NF * 64;
  __shared__ u16 Abuf[2][256 * 64];
  __shared__ u16 Bbuf[2][BN * 64];
  const int tid = threadIdx.x, lane = tid & 63, w = tid >> 6;
  const int wm = w >> 2, wn = w & 3;
  const int g = lane >> 4, l16 = lane & 15;

  const int per = gridDim.x >> 3;
  const int swz = ((int)blockIdx.x & 7) * per + ((int)blockIdx.x >> 3);
  const int nx = N / BN;
  const int bx = swz % nx, by = swz / nx;
  const int brow = by << 8, bcol = bx * BN;
  const int nt = K >> 6;

  auto stage_Ah = [&](int h, int kt, int d) {
    char* lds = (char*)Abuf[d] + h * 16384;
#pragma unroll
    for (int i = 0; i < 2; ++i) {
      int idx = i * 512 + tid;
      int r = h * 128 + (idx >> 3);
      int c = ((idx & 7) * 16) ^ ((r & 7) << 4);
      gload_lds16((const char*)(A + (size_t)(brow + r) * K + kt * 64) + c,
                  lds + idx * 16);
    }
  };
  auto stage_B = [&](int kt, int d) {
    char* lds = (char*)Bbuf[d];
#pragma unroll
    for (int i = 0; i < NF; ++i) {
      int idx = i * 512 + tid;
      int r = idx >> 3;
      int c = ((idx & 7) * 16) ^ ((r & 7) << 4);
      gload_lds16((const char*)(Bm + (size_t)(bcol + r) * K + kt * 64) + c,
                  lds + idx * 16);
    }
  };

  f32x4 acc[8][NF] = {};
  bf16x8 afr[4][2], bfr[NF][2];

  auto lda = [&](int d, int mf0) {
#pragma unroll
    for (int mf = 0; mf < 4; ++mf) {
      int r = wm * 128 + (mf0 + mf) * 16 + l16;
      const char* base = (const char*)Abuf[d] + r * 128;
      int sw = (r & 7) << 4;
#pragma unroll
      for (int ks = 0; ks < 2; ++ks)
        afr[mf][ks] = *(const bf16x8*)(base + ((ks * 64 + g * 16) ^ sw));
    }
  };
  auto ldb = [&](int d) {
#pragma unroll
    for (int nf = 0; nf < NF; ++nf) {
      int r = wn * (NF * 16) + nf * 16 + l16;
      const char* base = (const char*)Bbuf[d] + r * 128;
      int sw = (r & 7) << 4;
#pragma unroll
      for (int ks = 0; ks < 2; ++ks)
        bfr[nf][ks] = *(const bf16x8*)(base + ((ks * 64 + g * 16) ^ sw));
    }
  };
  auto mma_half = [&](int mf0) {
    __builtin_amdgcn_s_setprio(1);
#pragma unroll
    for (int mf = 0; mf < 4; ++mf)
#pragma unroll
      for (int nf = 0; nf < NF; ++nf)
#pragma unroll
        for (int ks = 0; ks < 2; ++ks)
          acc[mf0 + mf][nf] = __builtin_amdgcn_mfma_f32_16x16x32_bf16(
              afr[mf][ks], bfr[nf][ks], acc[mf0 + mf][nf], 0, 0, 0);
    __builtin_amdgcn_s_setprio(0);
  };

#define WAIT_LGKM() do { \
    asm volatile("s_waitcnt lgkmcnt(0)" ::: "memory"); \
    __builtin_amdgcn_sched_barrier(0); } while (0)
#define WAIT_VM_NF() do { \
    if constexpr (NF == 3) asm volatile("s_waitcnt vmcnt(3)" ::: "memory"); \
    else                   asm volatile("s_waitcnt vmcnt(2)" ::: "memory"); \
    __builtin_amdgcn_sched_barrier(0); } while (0)

  stage_Ah(0, 0, 0); stage_Ah(1, 0, 0);
  stage_B(0, 0);
  stage_B(1, 1);
  WAIT_VM_NF();
  __builtin_amdgcn_s_barrier();

  for (int t = 0; t < nt; ++t) {
    const int cur = t & 1;
    lda(cur, 0); ldb(cur);
    if (t + 1 < nt) stage_Ah(0, t + 1, cur ^ 1);
    __builtin_amdgcn_s_barrier();
    WAIT_LGKM();
    mma_half(0);
    __builtin_amdgcn_s_barrier();
    lda(cur, 4);
    if (t + 1 < nt) stage_Ah(1, t + 1, cur ^ 1);
    if (t + 2 < nt) stage_B(t + 2, cur);
    __builtin_amdgcn_s_barrier();
    WAIT_LGKM();
    mma_half(4);
    if (t + 1 < nt) {
      if (t + 2 < nt) { WAIT_VM_NF(); }
      else {
        asm volatile("s_waitcnt vmcnt(0)" ::: "memory");
        __builtin_amdgcn_sched_barrier(0);
      }
      __builtin_amdgcn_s_barrier();
    }
  }
#undef WAIT_LGKM
#undef WAIT_VM_NF

  const size_t cb = (size_t)(brow + wm * 128) * N + bcol + wn * (NF * 16);
#pragma unroll
  for (int mf = 0; mf < 8; ++mf)
#pragma unroll
    for (int nf = 0; nf < NF; ++nf) {
      int col = nf * 16 + l16;
#pragma unroll
      for (int rr = 0; rr < 4; ++rr) {
        int row = mf * 16 + g * 4 + rr;
        store_out(C + cb + (size_t)row * N + col, acc[mf][nf][rr]);
      }
    }
}

// ---------- V transpose: QKV V-part [b,s,h*128+d] -> Vt [b,h,d,s] ----------
__global__ __launch_bounds__(256)
void transpose_v(const u16* __restrict__ QKV, u16* __restrict__ Vt) {
  __shared__ u16 t[64][72];
  const int tid = threadIdx.x;
  const int b = blockIdx.y >> 5;
  const int s0 = (blockIdx.y & 31) * 64;
  const int hd0 = blockIdx.x * 64;
  const int lr = tid >> 2, lc = (tid & 3) * 16;
  const u16* src = QKV + ((size_t)(b * 2048 + s0 + lr) * 6144 + 4096 + hd0 + lc);
  *(bf16x8*)&t[lr][lc]     = *(const bf16x8*)src;
  *(bf16x8*)&t[lr][lc + 8] = *(const bf16x8*)(src + 8);
  __syncthreads();
  u16 tmp[16];
#pragma unroll
  for (int j = 0; j < 16; ++j) tmp[j] = t[lc + j][lr];
  u16* dst = Vt + ((size_t)(b * 2048 + hd0 + lr) * 2048 + s0 + lc);
  *(bf16x8*)dst       = *(bf16x8*)tmp;
  *(bf16x8*)(dst + 8) = *(bf16x8*)(tmp + 8);
}

// ---------- causal flash attention v4 ----------
// v3 + T13 defer-max (skip O-rescale when max growth <= 8) + exp-skip for
// wave-uniformly masked kb blocks.
__global__ __launch_bounds__(256, 2)
void attn_fwd(const u16* __restrict__ QKV, const u16* __restrict__ Vt,
              u16* __restrict__ AO) {
  __shared__ u16 Ks[2][64 * 128];
  __shared__ u16 Vs[2][128 * 64];
  __shared__ u16 Ps[4][16 * 64];
  const int tid = threadIdx.x, lane = tid & 63, w = tid >> 6;
  const int g = lane >> 4, l16 = lane & 15;
  const int bh = blockIdx.y, b = bh >> 4, h = bh & 15;
  const int fold = blockIdx.x;
  const int pswz = (l16 & 7) << 4;

  for (int phase = 0; phase < 2; ++phase) {
    const int qt = phase == 0 ? fold : 31 - fold;
    const int q0 = qt * 64 + w * 16;

    bf16x8 qf[4];
    {
      const u16* qrow = QKV + ((size_t)(b * 2048 + q0 + l16) * 6144 + h * 128 + g * 8);
#pragma unroll
      for (int c = 0; c < 4; ++c) qf[c] = *(const bf16x8*)(qrow + c * 32);
    }
    f32x4 o[8] = {};
    float mrun = -INFINITY, lrun = 0.f;

    auto stage = [&](int it, int d) {
      int kv0 = it * 64;
#pragma unroll
      for (int i = 0; i < 4; ++i) {
        int idx = i * 256 + tid;
        {
          int row = idx >> 4;
          int scolb = ((idx & 15) * 16) ^ ((row & 7) << 4);
          gload_lds16((const char*)QKV +
                          ((size_t)(b * 2048 + kv0 + row) * 6144 + 2048 + h * 128) * 2 + scolb,
                      (char*)Ks[d] + idx * 16);
        }
        {
          int dd = idx >> 3;
          int vcolb = ((idx & 7) * 16) ^ ((dd & 7) << 4);
          gload_lds16((const char*)Vt + ((size_t)(bh * 128 + dd) * 2048 + kv0) * 2 + vcolb,
                      (char*)Vs[d] + idx * 16);
        }
      }
    };

    const int ntkv = qt + 1;
    stage(0, 0);
    for (int it = 0; it < ntkv; ++it) {
      const int kv0 = it * 64, cur = it & 1;
      if (it + 1 < ntkv) {
        stage(it + 1, cur ^ 1);                       // prefetch over this tile's compute
        asm volatile("s_waitcnt vmcnt(8)" ::: "memory");
      } else {
        asm volatile("s_waitcnt vmcnt(0)" ::: "memory");
      }
      __builtin_amdgcn_sched_barrier(0);
      __builtin_amdgcn_s_barrier();

      // swapped QK^T: s[kb][r] = S[k=kv0+kb*16+g*4+r][q=q0+l16]
      f32x4 s[4];
#pragma unroll
      for (int kb = 0; kb < 4; ++kb) {
        if (kv0 + kb * 16 > q0 + 15) {                // wave-uniform masked block
          s[kb] = f32x4{-INFINITY, -INFINITY, -INFINITY, -INFINITY};
          continue;
        }
        f32x4 a = {};
        int row = kb * 16 + l16;
        int swzk = (row & 7) << 4;
#pragma unroll
        for (int c = 0; c < 4; ++c) {
          bf16x8 kf = *(const bf16x8*)((const char*)Ks[cur] + row * 256 + ((c * 64 + g * 16) ^ swzk));
          a = __builtin_amdgcn_mfma_f32_16x16x32_bf16(kf, qf[c], a, 0, 0, 0);
        }
        s[kb] = a * 0.08838834764831845f;             // 1/sqrt(128)
      }
      if (kv0 == qt * 64) {                           // diagonal tile: elementwise mask
#pragma unroll
        for (int kb = 0; kb < 4; ++kb)
#pragma unroll
          for (int r = 0; r < 4; ++r)
            if (kv0 + kb * 16 + g * 4 + r > q0 + l16) s[kb][r] = -INFINITY;
      }

      // online-softmax stats for q = q0 + l16 (scalar per thread)
      float mloc = -INFINITY;
#pragma unroll
      for (int kb = 0; kb < 4; ++kb)
#pragma unroll
        for (int r = 0; r < 4; ++r) mloc = fmaxf(mloc, s[kb][r]);
      mloc = fmaxf(mloc, __shfl_xor(mloc, 16));
      mloc = fmaxf(mloc, __shfl_xor(mloc, 32));
      float mnew = fmaxf(mrun, mloc);
      // T13 defer-max: only rescale when growth exceeds threshold (wave-uniform)
      if (!__all(mnew - mrun <= 8.f)) {
        float al = __expf(mrun - mnew);
        mrun = mnew;
        lrun *= al;
        float alq[4];
#pragma unroll
        for (int r = 0; r < 4; ++r) alq[r] = __shfl(al, g * 4 + r);
#pragma unroll
        for (int db = 0; db < 8; ++db)
#pragma unroll
          for (int r = 0; r < 4; ++r) o[db][r] *= alq[r];
      }
      float rsum = 0.f;
#pragma unroll
      for (int kb = 0; kb < 4; ++kb) {
        if (kv0 + kb * 16 > q0 + 15) {                // masked: P=0, skip exps
          *(ushort4*)((char*)Ps[w] + l16 * 128 + ((kb * 32 + g * 8) ^ pswz)) = ushort4{0, 0, 0, 0};
          continue;
        }
        float p0 = __expf(s[kb][0] - mrun);
        float p1 = __expf(s[kb][1] - mrun);
        float p2 = __expf(s[kb][2] - mrun);
        float p3 = __expf(s[kb][3] - mrun);
        rsum += (p0 + p1) + (p2 + p3);
        ushort4 pk = { f2bf(p0), f2bf(p1), f2bf(p2), f2bf(p3) };
        *(ushort4*)((char*)Ps[w] + l16 * 128 + ((kb * 32 + g * 8) ^ pswz)) = pk;
      }
      rsum += __shfl_xor(rsum, 16);
      rsum += __shfl_xor(rsum, 32);
      lrun += rsum;

      // PV: A = P rows q=l16, B = V^T rows d
#pragma unroll
      for (int ks = 0; ks < 2; ++ks) {
        if (kv0 + ks * 32 > q0 + 15) continue;        // fully-masked k-slice (wave-uniform)
        bf16x8 pa = *(const bf16x8*)((const char*)Ps[w] + l16 * 128 + ((ks * 64 + g * 16) ^ pswz));
#pragma unroll
        for (int db = 0; db < 8; ++db) {
          int row = db * 16 + l16;
          int swzv = (row & 7) << 4;
          bf16x8 vf = *(const bf16x8*)((const char*)Vs[cur] + row * 128 + ((ks * 64 + g * 16) ^ swzv));
          o[db] = __builtin_amdgcn_mfma_f32_16x16x32_bf16(pa, vf, o[db], 0, 0, 0);
        }
      }
      __builtin_amdgcn_s_barrier();                   // buf[cur] reads done before restage
    }

    float rlq[4];
#pragma unroll
    for (int r = 0; r < 4; ++r) rlq[r] = 1.0f / __shfl(lrun, g * 4 + r);
#pragma unroll
    for (int r = 0; r < 4; ++r) {
      int q = q0 + g * 4 + r;
#pragma unroll
      for (int db = 0; db < 8; ++db)
        AO[(size_t)(b * 2048 + q) * 2048 + h * 128 + db * 16 + l16] = f2bf(o[db][r] * rlq[r]);
    }
  }
}

// ---------- launch ----------
extern "C" void kernel_launch(void* const* d_in, const int* in_sizes, int n_in,
                              void* d_out, int out_size, void* d_ws, size_t ws_size,
                              hipStream_t stream) {
  const float* x  = (const float*)d_in[0];
  const float* wq = (const float*)d_in[1];
  const float* wk = (const float*)d_in[2];
  const float* wv = (const float*)d_in[3];
  const float* wo = (const float*)d_in[4];
  float* out = (float*)d_out;

  char* ws = (char*)d_ws;
  u16* Xb   = (u16*)(ws);                         // 4096x2048        16 MB
  u16* Wqkv = (u16*)(ws + ((size_t)16 << 20));    // 6144x2048        24 MB
  u16* Wob  = (u16*)(ws + ((size_t)40 << 20));    // 2048x2048         8 MB
  u16* QKV  = (u16*)(ws + ((size_t)48 << 20));    // 4096x6144        48 MB
  u16* Vt   = (u16*)(ws + ((size_t)96 << 20));    // 2x16x128x2048    16 MB
  u16* AO   = (u16*)(ws + ((size_t)112 << 20));   // 4096x2048        16 MB

  cvt_f32_bf16<<<2048, 256, 0, stream>>>(x, Xb, 2 * 2048 * 2048);
  cvt3_f32_bf16<<<dim3(2048, 3), 256, 0, stream>>>(wq, wk, wv, Wqkv);
  cvt_f32_bf16<<<2048, 256, 0, stream>>>(wo, Wob, 2048 * 2048);

  // QKV: 4096x6144x2048, BM=256 BN=192 -> 512 blocks = 2 even rounds
  gemm2ph<3, u16><<<512, 512, 0, stream>>>(Xb, Wqkv, QKV, 4096, 6144, 2048);
  transpose_v<<<dim3(32, 64), 256, 0, stream>>>(QKV, Vt);
  attn_fwd<<<dim3(16, 32), 256, 0, stream>>>(QKV, Vt, AO);
  // WO: 4096x2048x2048, BM=256 BN=128 -> 256 blocks = 1 even round
  gemm2ph<2, float><<<256, 512, 0, stream>>>(AO, Wob, out, 4096, 2048, 2048);
}